// Round 29
// baseline (44.497 us; speedup 1.0000x reference)
//
#include <hip/hip_runtime.h>

// ---------------- problem constants ----------------
namespace {
constexpr int N_ = 2048, C_ = 128, I_ = 9, E_ = 10;
constexpr int NSLAB = 40;            // (e, dsel), slab = 4e + dsel
constexpr int M_ = 8;                // nodes per contraction block
constexpr int NCHUNK = 64;           // chunks per slab
constexpr int NT3 = 165;             // #sorted triples p<=q<=i
constexpr int NT2 = 45;              // #sorted pairs  p<=q

// workspace layout (units: 4-byte words), ~5 MB
constexpr int O_ORDER = 0;                      // int[N] nodes sorted by element
constexpr int O_BOFF  = N_;                     // int[E+1] (pad 16)
constexpr int O_A     = N_ + 16;                // V2S: [slab][12][C] float4
constexpr int S_A     = NSLAB * 12 * C_ * 4;
constexpr int O_B     = O_A + S_A;              // V3S: [slab][42][C] float4
constexpr int S_B     = NSLAB * 42 * C_ * 4;
constexpr int O_C     = O_B + S_B;              // V1 : [slab][3][C] float4
constexpr int S_C     = NSLAB * 3 * C_ * 4;
constexpr int S_V_ALL = S_A + S_B + S_C;        // 1,167,360 words
// prep grid: 1160 vpre blocks + 8 (bucket + pad)
constexpr int NB_VPRE = 1160;
constexpr int NB_PREP = NB_VPRE + 8;            // 1168
}

typedef float f32x4 __attribute__((ext_vector_type(4)));

__device__ __forceinline__ float f4lane(float4 v, int l) {
  return l == 0 ? v.x : l == 1 ? v.y : l == 2 ? v.z : v.w;
}

__device__ __forceinline__ void nt_store4(float4* p, float a, float b, float cc, float dd) {
  f32x4 v = {a, b, cc, dd};
  __builtin_nontemporal_store(v, (f32x4*)p);
}

// ---------------- kernel 1: PREP = vpre(+inline usym) | bucket ---------------
__global__ __launch_bounds__(256) void prep_kernel(
    const float* __restrict__ attrs,
    const float* __restrict__ U3_0, const float* __restrict__ U2_0, const float* __restrict__ U1_0,
    const float* __restrict__ W3_0, const float* __restrict__ W2_0, const float* __restrict__ W1_0,
    const float* __restrict__ U3_1, const float* __restrict__ U2_1, const float* __restrict__ U1_1,
    const float* __restrict__ W3_1, const float* __restrict__ W2_1, const float* __restrict__ W1_1,
    float* __restrict__ ws_f, int* __restrict__ ws_i) {
  int bid = blockIdx.x;
  int t = threadIdx.x;

  if (bid < NB_VPRE) {
    int xcd = bid & 7, j = bid >> 3;     // j in [0,145)
    int sg = j / 29, xp = j % 29;        // 5 slab-groups x 29 units
    int slab = xcd + 8 * sg;
    int e = slab >> 2, dsel = slab & 3;
    int d = dsel ? dsel - 1 : 0;
    const float* U3 = dsel ? U3_1 : U3_0;
    const float* U2 = dsel ? U2_1 : U2_0;
    const float* U1 = dsel ? U1_1 : U1_0;
    const float* W3 = dsel ? W3_1 : W3_0;
    const float* W2 = dsel ? W2_1 : W2_0;
    const float* W1 = dsel ? W1_1 : W1_0;
    int half = t >> 7, c = t & 127;
    __shared__ float sf[8][23];

    if (xp < 21) {
      if (t < 184) {
        int s8 = t / 23, k = t % 23;
        int tt = 8 * xp + s8;
        float v = 0.f;
        if (tt < NT3) {
          int rem = tt, p = 0;
          for (;;) { int tp = (9 - p) * (10 - p) / 2; if (rem < tp) break; rem -= tp; ++p; }
          int q = p;
          for (;;) { int ln = 9 - q; if (rem < ln) break; rem -= ln; ++q; }
          int i = q + rem;
          auto u3 = [&](int a, int b, int g) {
            return U3[(((d * 9 + a) * 9 + b) * 9 + g) * 23 + k];
          };
          if (p == q && q == i)  v = u3(p, p, p);
          else if (p == q)       v = u3(p, p, i) + u3(p, i, p) + u3(i, p, p);
          else if (q == i)       v = u3(p, q, q) + u3(q, p, q) + u3(q, q, p);
          else                   v = u3(p, q, i) + u3(p, i, q) + u3(q, p, i)
                                   + u3(q, i, p) + u3(i, p, q) + u3(i, q, p);
        }
        sf[s8][k] = v;
      }
      __syncthreads();
      int sidx = 2 * xp + half;
      float acc[4] = {0.f, 0.f, 0.f, 0.f};
      for (int k = 0; k < 23; ++k) {
        float w = W3[(e * 23 + k) * C_ + c];
        #pragma unroll
        for (int l = 0; l < 4; ++l) acc[l] = fmaf(sf[half * 4 + l][k], w, acc[l]);
      }
      nt_store4(&((float4*)(ws_f + O_B))[((size_t)slab * 42 + sidx) * C_ + c],
                acc[0], acc[1], acc[2], acc[3]);
    } else if (xp < 27) {
      if (t < 64) {
        int s8 = t / 8, k = t % 8;
        int jj = 8 * (xp - 21) + s8;
        float v = 0.f;
        if (jj < NT2) {
          int rem = jj, p = 0;
          while (rem >= 9 - p) { rem -= 9 - p; ++p; }
          int q = p + rem;
          auto u2 = [&](int a, int b) { return U2[((d * 9 + a) * 9 + b) * 8 + k]; };
          v = (p == q) ? u2(p, p) : u2(p, q) + u2(q, p);
        }
        sf[s8][k] = v;
      }
      __syncthreads();
      int a = 2 * (xp - 21) + half;
      float acc[4] = {0.f, 0.f, 0.f, 0.f};
      for (int k = 0; k < 8; ++k) {
        float w = W2[(e * 8 + k) * C_ + c];
        #pragma unroll
        for (int l = 0; l < 4; ++l) acc[l] = fmaf(sf[half * 4 + l][k], w, acc[l]);
      }
      nt_store4(&((float4*)(ws_f + O_A))[((size_t)slab * 12 + a) * C_ + c],
                acc[0], acc[1], acc[2], acc[3]);
    } else {
      int ci, p0;
      if (xp == 27) { ci = half; p0 = 4 * half; }
      else { if (half) return; ci = 2; p0 = 8; }
      float acc[4] = {0.f, 0.f, 0.f, 0.f};
      for (int k = 0; k < 3; ++k) {
        float w = W1[(e * 3 + k) * C_ + c];
        #pragma unroll
        for (int l = 0; l < 4; ++l)
          if (p0 + l < 9) acc[l] = fmaf(U1[(d * 9 + p0 + l) * 3 + k], w, acc[l]);
      }
      nt_store4(&((float4*)(ws_f + O_C))[((size_t)slab * 3 + ci) * C_ + c],
                acc[0], acc[1], acc[2], acc[3]);
    }
  } else if (bid == NB_VPRE) {
    __shared__ int cnt[E_], base_s[E_ + 1], cur[E_];
    __shared__ short elem_s[N_];
    if (t < E_) cnt[t] = 0;
    __syncthreads();
    for (int n = t; n < N_; n += 256) {
      const float* a = attrs + n * E_;
      int best = 0; float bv = a[0];
      for (int e = 1; e < E_; ++e) { float v = a[e]; if (v > bv) { bv = v; best = e; } }
      elem_s[n] = (short)best;
      atomicAdd(&cnt[best], 1);
    }
    __syncthreads();
    if (t == 0) {
      int s = 0;
      for (int e = 0; e < E_; ++e) { base_s[e] = s; cur[e] = s; s += cnt[e]; }
      base_s[E_] = s;
    }
    __syncthreads();
    for (int n = t; n < N_; n += 256) {
      int p = atomicAdd(&cur[elem_s[n]], 1);
      ws_i[O_ORDER + p] = n;
    }
    if (t <= E_) ws_i[O_BOFF + t] = base_s[t];
  }
}

// ---------------- kernel 1b: WARM — stream V, x, Wlin into cache clean -------
// Massive-TLP coalesced float4 reads; latency fully overlapped. Recreates the
// R16 hot-dup regime (measured 18.5 us contract) before the contract runs.
// Loads kept live via empty inline asm (no DCE), no stores -> deterministic.
__global__ __launch_bounds__(256) void warm_kernel(
    const float* __restrict__ ws_f, const float* __restrict__ x,
    const float* __restrict__ Wlin0, const float* __restrict__ Wlin1) {
  int tid = blockIdx.x * 256 + threadIdx.x;
  int stride = gridDim.x * 256;
  float acc = 0.f;
  const float4* v4 = (const float4*)(ws_f + O_A);
  for (int i = tid; i < S_V_ALL / 4; i += stride) {
    float4 v = v4[i];
    acc += v.x + v.y + v.z + v.w;
  }
  const float4* x4 = (const float4*)x;
  for (int i = tid; i < N_ * C_ * I_ / 4; i += stride) {
    float4 v = x4[i];
    acc += v.x + v.w;
  }
  const float4* w0 = (const float4*)Wlin0;
  const float4* w1 = (const float4*)Wlin1;
  for (int i = tid; i < C_ * C_ / 4; i += stride) {
    float4 a = w0[i], b = w1[i];
    acc += a.x + b.x;
  }
  asm volatile("" :: "v"(acc));   // keep loads live, no output
}

// ---------------- contraction accumulator over all folded terms --------------
__device__ __forceinline__ void accum_all(const float4* __restrict__ A4,
                                          const float4* __restrict__ B4,
                                          const float4* __restrict__ C4,
                                          const float (&xm)[M_][I_], float (&f)[M_]) {
  #pragma unroll
  for (int p = 0; p < 9; ++p) {
    #pragma unroll
    for (int q = p; q < 9; ++q) {
      const int j  = 45 - (9 - p) * (10 - p) / 2 + (q - p);
      const int tb = 165 - (9 - p) * (10 - p) * (11 - p) / 6
                   + (9 - p) * (10 - p) / 2 - (9 - q) * (10 - q) / 2 - q;
      float s2 = f4lane(A4[(j >> 2) * C_], j & 3);
      float tv[M_];
      #pragma unroll
      for (int m = 0; m < M_; ++m) tv[m] = s2;
      #pragma unroll
      for (int i = q; i < 9; ++i) {
        const int tt = tb + i;
        float v = f4lane(B4[(tt >> 2) * C_], tt & 3);
        #pragma unroll
        for (int m = 0; m < M_; ++m) tv[m] = fmaf(xm[m][i], v, tv[m]);
      }
      #pragma unroll
      for (int m = 0; m < M_; ++m)
        f[m] = fmaf(xm[m][p] * xm[m][q], tv[m], f[m]);
    }
  }
  #pragma unroll
  for (int p = 0; p < 9; ++p) {
    float v = f4lane(C4[(p >> 2) * C_], p & 3);
    #pragma unroll
    for (int m = 0; m < M_; ++m) f[m] = fmaf(xm[m][p], v, f[m]);
  }
}

// ------ kernel 2: contraction + fused linear/sc epilogue (R22 geometry) ------
__global__ __launch_bounds__(128) void contract12_kernel(
    const float* __restrict__ x, const float* __restrict__ ws_f,
    const int* __restrict__ ws_i,
    const float* __restrict__ Wlin0, const float* __restrict__ Wlin1,
    const float* __restrict__ sc, float* __restrict__ out) {
  int bid = blockIdx.x;
  int xcd = bid & 7;
  int sg  = (bid >> 3) % 5;
  int chunk = bid / 40;
  int slab = xcd + 8 * sg;
  int e = slab >> 2, dsel = slab & 3;
  int b0 = ws_i[O_BOFF + e];
  int cnt_e = ws_i[O_BOFF + e + 1] - b0;
  int base = chunk * M_;
  if (base >= cnt_e) return;            // block-uniform
  int cnt = cnt_e - base; if (cnt > M_) cnt = M_;
  int c = threadIdx.x;

  const float4* A4 = (const float4*)(ws_f + O_A) + (size_t)slab * 12 * C_ + c;
  const float4* B4 = (const float4*)(ws_f + O_B) + (size_t)slab * 42 * C_ + c;
  const float4* C4 = (const float4*)(ws_f + O_C) + (size_t)slab * 3 * C_ + c;

  int nn[M_];
  #pragma unroll
  for (int m = 0; m < M_; ++m) {
    int idx = base + m; if (idx >= cnt_e) idx = cnt_e - 1;
    nn[m] = ws_i[O_ORDER + b0 + idx];
  }
  float xm[M_][I_];
  #pragma unroll
  for (int m = 0; m < M_; ++m) {
    const float* xp = x + ((size_t)nn[m] * C_ + c) * I_;
    #pragma unroll
    for (int i = 0; i < I_; ++i) xm[m][i] = xp[i];
  }
  float f[M_];
  #pragma unroll
  for (int m = 0; m < M_; ++m) f[m] = 0.f;

  accum_all(A4, B4, C4, xm, f);

  // ---- fused equivariant linear + skip ----
  __shared__ float fs[M_][C_ + 1];
  #pragma unroll
  for (int m = 0; m < M_; ++m) fs[m][c] = f[m];
  __syncthreads();

  const float* Wl = (dsel == 0) ? Wlin0 : Wlin1;
  float acc[M_];
  #pragma unroll
  for (int m = 0; m < M_; ++m) acc[m] = 0.f;
  #pragma unroll 8
  for (int u = 0; u < C_; ++u) {
    float wv = Wl[u * C_ + c];
    #pragma unroll
    for (int m = 0; m < M_; ++m) acc[m] = fmaf(fs[m][u], wv, acc[m]);
  }
  constexpr float inv = 0.08838834764831843f;  // 1/sqrt(128)
  int col = (dsel == 0) ? c : C_ + c * 3 + (dsel - 1);
  #pragma unroll
  for (int m = 0; m < M_; ++m) {
    if (m < cnt) {
      int o = nn[m] * 512 + col;
      out[o] = acc[m] * inv + sc[o];
    }
  }
}

// ---------------- launcher ---------------------------------------------------
extern "C" void kernel_launch(void* const* d_in, const int* in_sizes, int n_in,
                              void* d_out, int out_size, void* d_ws, size_t ws_size,
                              hipStream_t stream) {
  const float* node_feats = (const float*)d_in[0];
  const float* sc         = (const float*)d_in[1];
  const float* node_attrs = (const float*)d_in[2];
  const float* U3_0 = (const float*)d_in[3];
  const float* U2_0 = (const float*)d_in[4];
  const float* U1_0 = (const float*)d_in[5];
  const float* W3_0 = (const float*)d_in[6];
  const float* W2_0 = (const float*)d_in[7];
  const float* W1_0 = (const float*)d_in[8];
  const float* U3_1 = (const float*)d_in[9];
  const float* U2_1 = (const float*)d_in[10];
  const float* U1_1 = (const float*)d_in[11];
  const float* W3_1 = (const float*)d_in[12];
  const float* W2_1 = (const float*)d_in[13];
  const float* W1_1 = (const float*)d_in[14];
  const float* Wlin0 = (const float*)d_in[15];
  const float* Wlin1 = (const float*)d_in[16];

  float* ws_f = (float*)d_ws;
  int*   ws_i = (int*)d_ws;

  prep_kernel<<<NB_PREP, 256, 0, stream>>>(
      node_attrs,
      U3_0, U2_0, U1_0, W3_0, W2_0, W1_0,
      U3_1, U2_1, U1_1, W3_1, W2_1, W1_1, ws_f, ws_i);

  warm_kernel<<<1024, 256, 0, stream>>>(ws_f, node_feats, Wlin0, Wlin1);

  contract12_kernel<<<NSLAB * NCHUNK, 128, 0, stream>>>(
      node_feats, ws_f, ws_i, Wlin0, Wlin1, sc, (float*)d_out);
}

// Round 30
// 41.324 us; speedup vs baseline: 1.0768x; 1.0768x over previous
//
#include <hip/hip_runtime.h>

// ---------------- problem constants ----------------
namespace {
constexpr int N_ = 2048, C_ = 128, I_ = 9, E_ = 10;
constexpr int NSLAB = 40;            // (e, dsel), slab = 4e + dsel
constexpr int M_ = 8;                // nodes per contraction block
constexpr int NCHUNK = 64;           // chunks per slab (8*64 = 512-node cap/elem)
constexpr int NT3 = 165;             // #sorted triples p<=q<=i
constexpr int NT2 = 45;              // #sorted pairs  p<=q

// workspace layout (units: 4-byte words), ~5 MB
constexpr int O_ORDER = 0;                      // int[N] nodes sorted by element
constexpr int O_BOFF  = N_;                     // int[E+1] (pad 16)
constexpr int O_A     = N_ + 16;                // V2S: [slab][12][C] float4 (45/48 used)
constexpr int S_A     = NSLAB * 12 * C_ * 4;
constexpr int O_B     = O_A + S_A;              // V3S: [slab][42][C] float4 (165/168 used)
constexpr int S_B     = NSLAB * 42 * C_ * 4;
constexpr int O_C     = O_B + S_B;              // V1 : [slab][3][C] float4 (9/12 used)
constexpr int S_C     = NSLAB * 3 * C_ * 4;
// prep grid: 1160 vpre blocks (8 XCD-pinned groups of 145) + 8 (bucket + pad)
constexpr int NB_VPRE = 1160;
constexpr int NB_PREP = NB_VPRE + 8;            // 1168 (multiple of 8)
}

__device__ __forceinline__ float f4lane(float4 v, int l) {
  return l == 0 ? v.x : l == 1 ? v.y : l == 2 ? v.z : v.w;
}

// ---------------- kernel 1: PREP = XCD-pinned vpre(+inline usym) | bucket ----
__global__ __launch_bounds__(256) void prep_kernel(
    const float* __restrict__ attrs,
    const float* __restrict__ U3_0, const float* __restrict__ U2_0, const float* __restrict__ U1_0,
    const float* __restrict__ W3_0, const float* __restrict__ W2_0, const float* __restrict__ W1_0,
    const float* __restrict__ U3_1, const float* __restrict__ U2_1, const float* __restrict__ U1_1,
    const float* __restrict__ W3_1, const float* __restrict__ W2_1, const float* __restrict__ W1_1,
    float* __restrict__ ws_f, int* __restrict__ ws_i) {
  int bid = blockIdx.x;
  int t = threadIdx.x;

  if (bid < NB_VPRE) {
    int xcd = bid & 7, j = bid >> 3;     // j in [0,145)
    int sg = j / 29, xp = j % 29;        // 5 slab-groups x 29 units
    int slab = xcd + 8 * sg;             // slab%8 == xcd
    int e = slab >> 2, dsel = slab & 3;
    int d = dsel ? dsel - 1 : 0;
    const float* U3 = dsel ? U3_1 : U3_0;
    const float* U2 = dsel ? U2_1 : U2_0;
    const float* U1 = dsel ? U1_1 : U1_0;
    const float* W3 = dsel ? W3_1 : W3_0;
    const float* W2 = dsel ? W2_1 : W2_0;
    const float* W1 = dsel ? W1_1 : W1_0;
    int half = t >> 7, c = t & 127;
    __shared__ float sf[8][23];

    if (xp < 21) {
      if (t < 184) {
        int s8 = t / 23, k = t % 23;
        int tt = 8 * xp + s8;
        float v = 0.f;
        if (tt < NT3) {
          int rem = tt, p = 0;
          for (;;) { int tp = (9 - p) * (10 - p) / 2; if (rem < tp) break; rem -= tp; ++p; }
          int q = p;
          for (;;) { int ln = 9 - q; if (rem < ln) break; rem -= ln; ++q; }
          int i = q + rem;
          auto u3 = [&](int a, int b, int g) {
            return U3[(((d * 9 + a) * 9 + b) * 9 + g) * 23 + k];
          };
          if (p == q && q == i)  v = u3(p, p, p);
          else if (p == q)       v = u3(p, p, i) + u3(p, i, p) + u3(i, p, p);
          else if (q == i)       v = u3(p, q, q) + u3(q, p, q) + u3(q, q, p);
          else                   v = u3(p, q, i) + u3(p, i, q) + u3(q, p, i)
                                   + u3(q, i, p) + u3(i, p, q) + u3(i, q, p);
        }
        sf[s8][k] = v;
      }
      __syncthreads();
      int sidx = 2 * xp + half;
      float acc[4] = {0.f, 0.f, 0.f, 0.f};
      for (int k = 0; k < 23; ++k) {
        float w = W3[(e * 23 + k) * C_ + c];
        #pragma unroll
        for (int l = 0; l < 4; ++l) acc[l] = fmaf(sf[half * 4 + l][k], w, acc[l]);
      }
      ((float4*)(ws_f + O_B))[((size_t)slab * 42 + sidx) * C_ + c] =
          make_float4(acc[0], acc[1], acc[2], acc[3]);
    } else if (xp < 27) {
      if (t < 64) {
        int s8 = t / 8, k = t % 8;
        int jj = 8 * (xp - 21) + s8;
        float v = 0.f;
        if (jj < NT2) {
          int rem = jj, p = 0;
          while (rem >= 9 - p) { rem -= 9 - p; ++p; }
          int q = p + rem;
          auto u2 = [&](int a, int b) { return U2[((d * 9 + a) * 9 + b) * 8 + k]; };
          v = (p == q) ? u2(p, p) : u2(p, q) + u2(q, p);
        }
        sf[s8][k] = v;
      }
      __syncthreads();
      int a = 2 * (xp - 21) + half;
      float acc[4] = {0.f, 0.f, 0.f, 0.f};
      for (int k = 0; k < 8; ++k) {
        float w = W2[(e * 8 + k) * C_ + c];
        #pragma unroll
        for (int l = 0; l < 4; ++l) acc[l] = fmaf(sf[half * 4 + l][k], w, acc[l]);
      }
      ((float4*)(ws_f + O_A))[((size_t)slab * 12 + a) * C_ + c] =
          make_float4(acc[0], acc[1], acc[2], acc[3]);
    } else {
      int ci, p0;
      if (xp == 27) { ci = half; p0 = 4 * half; }
      else { if (half) return; ci = 2; p0 = 8; }
      float acc[4] = {0.f, 0.f, 0.f, 0.f};
      for (int k = 0; k < 3; ++k) {
        float w = W1[(e * 3 + k) * C_ + c];
        #pragma unroll
        for (int l = 0; l < 4; ++l)
          if (p0 + l < 9) acc[l] = fmaf(U1[(d * 9 + p0 + l) * 3 + k], w, acc[l]);
      }
      ((float4*)(ws_f + O_C))[((size_t)slab * 3 + ci) * C_ + c] =
          make_float4(acc[0], acc[1], acc[2], acc[3]);
    }
  } else if (bid == NB_VPRE) {
    __shared__ int cnt[E_], base_s[E_ + 1], cur[E_];
    __shared__ short elem_s[N_];
    if (t < E_) cnt[t] = 0;
    __syncthreads();
    for (int n = t; n < N_; n += 256) {
      const float* a = attrs + n * E_;
      int best = 0; float bv = a[0];
      for (int e = 1; e < E_; ++e) { float v = a[e]; if (v > bv) { bv = v; best = e; } }
      elem_s[n] = (short)best;
      atomicAdd(&cnt[best], 1);
    }
    __syncthreads();
    if (t == 0) {
      int s = 0;
      for (int e = 0; e < E_; ++e) { base_s[e] = s; cur[e] = s; s += cnt[e]; }
      base_s[E_] = s;
    }
    __syncthreads();
    for (int n = t; n < N_; n += 256) {
      int p = atomicAdd(&cur[elem_s[n]], 1);
      ws_i[O_ORDER + p] = n;
    }
    if (t <= E_) ws_i[O_BOFF + t] = base_s[t];
  }
}

// ---------------- p-row software pipeline for the folded contraction ---------
// Row P of the term list: pairs (P,q) q=P..8 and triples (P,q,i). Spans:
template<int P> struct Row {
  static constexpr int T0 = 165 - (9 - P) * (10 - P) * (11 - P) / 6;
  static constexpr int T1 = 165 - (8 - P) * (9 - P) * (10 - P) / 6;
  static constexpr int BL = T0 >> 2;               // first B float4
  static constexpr int BH = (T1 - 1) >> 2;         // last B float4 (<= BL+11)
  static constexpr int J0 = 45 - (9 - P) * (10 - P) / 2;
  static constexpr int JL = J0 >> 2;
  static constexpr int JH = (J0 + 8 - P) >> 2;
};

template<int P>
__device__ __forceinline__ void load_row(const float4* __restrict__ A4,
                                         const float4* __restrict__ B4,
                                         float4 (&vb)[12], float4 (&va)[3]) {
  #pragma unroll
  for (int k = Row<P>::BL; k <= Row<P>::BH; ++k) vb[k - Row<P>::BL] = B4[k * C_];
  #pragma unroll
  for (int k = Row<P>::JL; k <= Row<P>::JH; ++k) va[k - Row<P>::JL] = A4[k * C_];
}

template<int P>
__device__ __forceinline__ void compute_row(const float4 (&vb)[12], const float4 (&va)[3],
                                            const float (&xm)[M_][I_], float (&f)[M_]) {
  #pragma unroll
  for (int q = P; q < 9; ++q) {
    const int j  = Row<P>::J0 + (q - P);
    const int tb = Row<P>::T0 + (9 - P) * (10 - P) / 2 - (9 - q) * (10 - q) / 2 - q
                 - Row<P>::T0 + Row<P>::T0;  // == original tb formula
    float s2 = f4lane(va[(j >> 2) - Row<P>::JL], j & 3);
    float tv[M_];
    #pragma unroll
    for (int m = 0; m < M_; ++m) tv[m] = s2;
    #pragma unroll
    for (int i = q; i < 9; ++i) {
      const int tt = tb + i;
      float v = f4lane(vb[(tt >> 2) - Row<P>::BL], tt & 3);
      #pragma unroll
      for (int m = 0; m < M_; ++m) tv[m] = fmaf(xm[m][i], v, tv[m]);
    }
    #pragma unroll
    for (int m = 0; m < M_; ++m)
      f[m] = fmaf(xm[m][P] * xm[m][q], tv[m], f[m]);
  }
}

template<int P>
__device__ __forceinline__ void rows(const float4* __restrict__ A4,
                                     const float4* __restrict__ B4,
                                     float4 (&vb)[12], float4 (&va)[3],
                                     const float (&xm)[M_][I_], float (&f)[M_]) {
  float4 nvb[12]; float4 nva[3];
  if constexpr (P < 8) load_row<P + 1>(A4, B4, nvb, nva);   // issue next row's loads
  compute_row<P>(vb, va, xm, f);                            // compute current row
  if constexpr (P < 8) rows<P + 1>(A4, B4, nvb, nva, xm, f);
}

// ------ kernel 2: XCD-pinned contraction + fused linear/sc epilogue ----------
__global__ __launch_bounds__(128, 1) void contract13_kernel(
    const float* __restrict__ x, const float* __restrict__ ws_f,
    const int* __restrict__ ws_i,
    const float* __restrict__ Wlin0, const float* __restrict__ Wlin1,
    const float* __restrict__ sc, float* __restrict__ out) {
  int bid = blockIdx.x;
  int xcd = bid & 7;
  int sg  = (bid >> 3) % 5;
  int chunk = bid / 40;
  int slab = xcd + 8 * sg;              // slab%8 == bid%8
  int e = slab >> 2, dsel = slab & 3;
  int b0 = ws_i[O_BOFF + e];
  int cnt_e = ws_i[O_BOFF + e + 1] - b0;
  int base = chunk * M_;
  if (base >= cnt_e) return;            // block-uniform
  int cnt = cnt_e - base; if (cnt > M_) cnt = M_;
  int c = threadIdx.x;

  const float4* A4 = (const float4*)(ws_f + O_A) + (size_t)slab * 12 * C_ + c;
  const float4* B4 = (const float4*)(ws_f + O_B) + (size_t)slab * 42 * C_ + c;
  const float4* C4 = (const float4*)(ws_f + O_C) + (size_t)slab * 3 * C_ + c;

  int nn[M_];
  #pragma unroll
  for (int m = 0; m < M_; ++m) {
    int idx = base + m; if (idx >= cnt_e) idx = cnt_e - 1;
    nn[m] = ws_i[O_ORDER + b0 + idx];
  }
  // V1 (3 float4) issued early; consumed at the very end
  float4 c4buf[3];
  #pragma unroll
  for (int k = 0; k < 3; ++k) c4buf[k] = C4[k * C_];

  float xm[M_][I_];
  #pragma unroll
  for (int m = 0; m < M_; ++m) {
    const float* xp = x + ((size_t)nn[m] * C_ + c) * I_;
    #pragma unroll
    for (int i = 0; i < I_; ++i) xm[m][i] = xp[i];
  }
  float f[M_];
  #pragma unroll
  for (int m = 0; m < M_; ++m) f[m] = 0.f;

  // ---- software-pipelined term rows: load row P+1 while computing row P ----
  {
    float4 vb[12]; float4 va[3];
    load_row<0>(A4, B4, vb, va);
    rows<0>(A4, B4, vb, va, xm, f);
  }
  // V1 term
  #pragma unroll
  for (int p = 0; p < 9; ++p) {
    float v = f4lane(c4buf[p >> 2], p & 3);
    #pragma unroll
    for (int m = 0; m < M_; ++m) f[m] = fmaf(xm[m][p], v, f[m]);
  }

  // ---- fused equivariant linear + skip ----
  __shared__ float fs[M_][C_ + 1];
  #pragma unroll
  for (int m = 0; m < M_; ++m) fs[m][c] = f[m];
  __syncthreads();

  const float* Wl = (dsel == 0) ? Wlin0 : Wlin1;
  float acc[M_];
  #pragma unroll
  for (int m = 0; m < M_; ++m) acc[m] = 0.f;
  #pragma unroll 8
  for (int u = 0; u < C_; ++u) {
    float wv = Wl[u * C_ + c];
    #pragma unroll
    for (int m = 0; m < M_; ++m) acc[m] = fmaf(fs[m][u], wv, acc[m]);
  }
  constexpr float inv = 0.08838834764831843f;  // 1/sqrt(128)
  int col = (dsel == 0) ? c : C_ + c * 3 + (dsel - 1);
  #pragma unroll
  for (int m = 0; m < M_; ++m) {
    if (m < cnt) {
      int o = nn[m] * 512 + col;
      out[o] = acc[m] * inv + sc[o];
    }
  }
}

// ---------------- launcher ---------------------------------------------------
extern "C" void kernel_launch(void* const* d_in, const int* in_sizes, int n_in,
                              void* d_out, int out_size, void* d_ws, size_t ws_size,
                              hipStream_t stream) {
  const float* node_feats = (const float*)d_in[0];
  const float* sc         = (const float*)d_in[1];
  const float* node_attrs = (const float*)d_in[2];
  const float* U3_0 = (const float*)d_in[3];
  const float* U2_0 = (const float*)d_in[4];
  const float* U1_0 = (const float*)d_in[5];
  const float* W3_0 = (const float*)d_in[6];
  const float* W2_0 = (const float*)d_in[7];
  const float* W1_0 = (const float*)d_in[8];
  const float* U3_1 = (const float*)d_in[9];
  const float* U2_1 = (const float*)d_in[10];
  const float* U1_1 = (const float*)d_in[11];
  const float* W3_1 = (const float*)d_in[12];
  const float* W2_1 = (const float*)d_in[13];
  const float* W1_1 = (const float*)d_in[14];
  const float* Wlin0 = (const float*)d_in[15];
  const float* Wlin1 = (const float*)d_in[16];

  float* ws_f = (float*)d_ws;
  int*   ws_i = (int*)d_ws;

  prep_kernel<<<NB_PREP, 256, 0, stream>>>(
      node_attrs,
      U3_0, U2_0, U1_0, W3_0, W2_0, W1_0,
      U3_1, U2_1, U1_1, W3_1, W2_1, W1_1, ws_f, ws_i);

  contract13_kernel<<<NSLAB * NCHUNK, 128, 0, stream>>>(
      node_feats, ws_f, ws_i, Wlin0, Wlin1, sc, (float*)d_out);
}